// Round 4
// baseline (544.111 us; speedup 1.0000x reference)
//
#include <hip/hip_runtime.h>

#define SEQ   2048
#define NHEAD 16
#define DKK   64
#define HID   1024

typedef __attribute__((ext_vector_type(8))) short bf16x8;
typedef __attribute__((ext_vector_type(4))) float f32x4;

__device__ __forceinline__ unsigned short f32_bf16(float f) {
    unsigned int u = __builtin_bit_cast(unsigned int, f);
    u += 0x7fffu + ((u >> 16) & 1u);
    return (unsigned short)(u >> 16);
}

__device__ __forceinline__ unsigned int pack_bf16x2(float a, float b) {
    return (unsigned int)f32_bf16(a) | ((unsigned int)f32_bf16(b) << 16);
}

// load 8 consecutive fp32 and pack to a bf16 A/B fragment
__device__ __forceinline__ bf16x8 load_f32x8_bf16(const float* __restrict__ p) {
    float4 a = *(const float4*)p;
    float4 b = *(const float4*)(p + 4);
    union { bf16x8 v; uint4 u; } r;
    r.u = make_uint4(pack_bf16x2(a.x, a.y), pack_bf16x2(a.z, a.w),
                     pack_bf16x2(b.x, b.y), pack_bf16x2(b.z, b.w));
    return r.v;
}

// ---------------------------------------------------------------------------
// Kernel 1: QKV projections, LDS-free.  Both MFMA operand layouts are direct
// 32B/lane contiguous global reads (A[m=l15][k=quad*8+j], B likewise), so we
// read fragments straight from global (L2/L3-resident working set) and let
// the compiler pipeline the k-loop with zero barriers.
// Outputs: Qh/Kh = [b, h, s, d] bf16; V transposed: Vt = [b, h, d, s] bf16.
// ---------------------------------------------------------------------------
__global__ __launch_bounds__(256, 2)
void proj_kernel(const float* __restrict__ qin, const float* __restrict__ kin,
                 const float* __restrict__ vin,
                 const float* __restrict__ Wq, const float* __restrict__ bq_,
                 const float* __restrict__ Wk, const float* __restrict__ bk_,
                 const float* __restrict__ Wv, const float* __restrict__ bv_,
                 unsigned short* __restrict__ Qh, unsigned short* __restrict__ Kh,
                 unsigned short* __restrict__ Vt)
{
    const int z = blockIdx.z;
    const float* X; const float* W; const float* bias;
    if (z == 0)      { X = qin; W = Wq; bias = bq_; }
    else if (z == 1) { X = kin; W = Wk; bias = bk_; }
    else             { X = vin; W = Wv; bias = bv_; }

    const int m0 = blockIdx.x * 128;
    const int n0 = blockIdx.y * 128;
    const int tid  = threadIdx.x;
    const int lane = tid & 63, wid = tid >> 6;
    const int wm = (wid >> 1) * 64, wn = (wid & 1) * 64;
    const int l15 = lane & 15, quad = lane >> 4;

    const float* Arow[4];
    const float* Brow[4];
    #pragma unroll
    for (int i = 0; i < 4; ++i) {
        Arow[i] = X + (size_t)(m0 + wm + i * 16 + l15) * HID + quad * 8;
        Brow[i] = W + (size_t)(n0 + wn + i * 16 + l15) * HID + quad * 8;
    }

    f32x4 acc[4][4];
    #pragma unroll
    for (int i = 0; i < 4; ++i)
        #pragma unroll
        for (int j = 0; j < 4; ++j)
            acc[i][j] = f32x4{0.f, 0.f, 0.f, 0.f};

    for (int k0 = 0; k0 < HID; k0 += 32) {
        bf16x8 af[4], bfr[4];
        #pragma unroll
        for (int mi = 0; mi < 4; ++mi) af[mi] = load_f32x8_bf16(Arow[mi] + k0);
        #pragma unroll
        for (int ni = 0; ni < 4; ++ni) bfr[ni] = load_f32x8_bf16(Brow[ni] + k0);
        #pragma unroll
        for (int mi = 0; mi < 4; ++mi)
            #pragma unroll
            for (int ni = 0; ni < 4; ++ni)
                acc[mi][ni] = __builtin_amdgcn_mfma_f32_16x16x32_bf16(
                    af[mi], bfr[ni], acc[mi][ni], 0, 0, 0);
    }

    #pragma unroll
    for (int mi = 0; mi < 4; ++mi) {
        #pragma unroll
        for (int ni = 0; ni < 4; ++ni) {
            int n = n0 + wn + ni * 16 + l15;
            float bv = bias[n];
            int hh = n >> 6, d = n & 63;
            #pragma unroll
            for (int r = 0; r < 4; ++r) {
                int m = m0 + wm + mi * 16 + quad * 4 + r;
                int bb = m >> 11, s = m & 2047;
                unsigned short hv = f32_bf16(acc[mi][ni][r] + bv);
                if (z == 0)
                    Qh[((size_t)(bb * NHEAD + hh) * SEQ + s) * DKK + d] = hv;
                else if (z == 1)
                    Kh[((size_t)(bb * NHEAD + hh) * SEQ + s) * DKK + d] = hv;
                else
                    Vt[((size_t)(bb * NHEAD + hh) * DKK + d) * SEQ + s] = hv;
            }
        }
    }
}

// ---------------------------------------------------------------------------
// Kernel 2: split-K flash attention, no max tracking (logits bounded; masked
// logits are 1e-9 per reference => p = mask ? exp(s/8) : 1.0).  Block = 4
// waves over ONE 64-row q-tile; wave w handles k-tiles [8w, 8w+8).  K/V
// fragments load directly from global; zero block barriers in the k-loop.
// Ps write->read ordering within a wave is handled by the compiler's LDS
// alias analysis (in-order per-wave DS pipe) -- no explicit fences, so loads
// of strip/tile i+1 pipeline above strip i's LDS drain.
// Row sums via ones-MFMA; merge = plain sum of (O, l) partials.
// ---------------------------------------------------------------------------
__global__ __launch_bounds__(256, 2)
void attn_kernel(const unsigned short* __restrict__ Qh, const unsigned short* __restrict__ Kh,
                 const unsigned short* __restrict__ Vt, const int* __restrict__ mask,
                 unsigned short* __restrict__ Om)
{
    const int qt = blockIdx.x;       // 0..31 (q-tile of 64)
    const int h  = blockIdx.y;
    const int b  = blockIdx.z;
    const int tid  = threadIdx.x;
    const int lane = tid & 63, wid = tid >> 6;
    const int l15 = lane & 15, quad = lane >> 4;
    const int q0 = qt * 64;

    const size_t hoff = (size_t)(b * NHEAD + h) * SEQ * DKK;
    const unsigned short* Qp = Qh + hoff;
    const unsigned short* Kp = Kh + hoff;
    const unsigned short* Vp = Vt + hoff;   // [d][s]

    __shared__ __align__(16) unsigned short Ps[4][64 * 72];  // per-wave P buffer
    __shared__ float lbuf[4][64];
    float* obuf = (float*)&Ps[0][0];        // 64x66 f32 merge buffer (aliased)

    // Q fragments (A-operand layout), same q-tile for all 4 waves
    bf16x8 qf[4][2];
    #pragma unroll
    for (int mi = 0; mi < 4; ++mi)
        #pragma unroll
        for (int kc = 0; kc < 2; ++kc)
            qf[mi][kc] = *(const bf16x8*)(Qp + (size_t)(q0 + mi * 16 + l15) * DKK
                                          + kc * 32 + quad * 8);

    // ones B-fragment for row-sum MFMA
    bf16x8 onesf;
    #pragma unroll
    for (int i = 0; i < 8; ++i) onesf[i] = (short)0x3F80;

    f32x4 o_acc[4][4];
    f32x4 l_acc[4];
    #pragma unroll
    for (int mi = 0; mi < 4; ++mi) {
        #pragma unroll
        for (int nd = 0; nd < 4; ++nd) o_acc[mi][nd] = f32x4{0.f, 0.f, 0.f, 0.f};
        l_acc[mi] = f32x4{0.f, 0.f, 0.f, 0.f};
    }

    const float C = 0.125f * 1.44269504f;   // 1/sqrt(dk) * log2(e)

    const int ktBeg = wid * 8, ktEnd = ktBeg + 8;
    for (int kt = ktBeg; kt < ktEnd; ++kt) {
        const int kbase = kt * 64;
        // K and V fragments (B-operand) straight from global
        bf16x8 kb[2][4], vb[2][4];
        #pragma unroll
        for (int kc = 0; kc < 2; ++kc)
            #pragma unroll
            for (int ni = 0; ni < 4; ++ni) {
                kb[kc][ni] = *(const bf16x8*)(Kp + (size_t)(kbase + ni * 16 + l15) * DKK
                                              + kc * 32 + quad * 8);
                vb[kc][ni] = *(const bf16x8*)(Vp + (size_t)(ni * 16 + l15) * SEQ
                                              + kbase + kc * 32 + quad * 8);
            }

        #pragma unroll
        for (int mi = 0; mi < 4; ++mi) {
            // mask values for this 16-row strip
            int mv[4][4];
            #pragma unroll
            for (int r = 0; r < 4; ++r) {
                const int* mrow = mask + ((size_t)b * SEQ + q0 + mi * 16 + quad * 4 + r) * SEQ
                                  + kbase;
                #pragma unroll
                for (int ni = 0; ni < 4; ++ni) mv[r][ni] = mrow[ni * 16 + l15];
            }

            f32x4 s[4];
            #pragma unroll
            for (int ni = 0; ni < 4; ++ni) s[ni] = f32x4{0.f, 0.f, 0.f, 0.f};
            #pragma unroll
            for (int kc = 0; kc < 2; ++kc)
                #pragma unroll
                for (int ni = 0; ni < 4; ++ni)
                    s[ni] = __builtin_amdgcn_mfma_f32_16x16x32_bf16(
                        qf[mi][kc], kb[kc][ni], s[ni], 0, 0, 0);

            // p = mask ? exp2(s*C) : 1.0   (fixed max = 0; masked logit 1e-9 -> p=1)
            #pragma unroll
            for (int r = 0; r < 4; ++r) {
                unsigned short* prow = &Ps[wid][(mi * 16 + quad * 4 + r) * 72];
                #pragma unroll
                for (int ni = 0; ni < 4; ++ni) {
                    float p = mv[r][ni] ? exp2f(s[ni][r] * C) : 1.0f;
                    prow[ni * 16 + l15] = f32_bf16(p);
                }
            }

            // O += P V ; l += P @ 1   (compiler inserts the lgkm waits)
            #pragma unroll
            for (int kc = 0; kc < 2; ++kc) {
                bf16x8 pa = *(const bf16x8*)&Ps[wid][(mi * 16 + l15) * 72 + kc * 32 + quad * 8];
                l_acc[mi] = __builtin_amdgcn_mfma_f32_16x16x32_bf16(
                    pa, onesf, l_acc[mi], 0, 0, 0);
                #pragma unroll
                for (int nd = 0; nd < 4; ++nd)
                    o_acc[mi][nd] = __builtin_amdgcn_mfma_f32_16x16x32_bf16(
                        pa, vb[kc][nd], o_acc[mi][nd], 0, 0, 0);
            }
        }
    }

    // ---- merge 4 per-wave partial (O, l) by plain summation ----
    if (l15 == 0) {
        #pragma unroll
        for (int mi = 0; mi < 4; ++mi)
            #pragma unroll
            for (int r = 0; r < 4; ++r)
                lbuf[wid][mi * 16 + quad * 4 + r] = l_acc[mi][r];
    }
    __syncthreads();   // also fences last Ps reads before obuf aliasing

    if (wid == 0) {
        #pragma unroll
        for (int mi = 0; mi < 4; ++mi)
            #pragma unroll
            for (int nd = 0; nd < 4; ++nd)
                #pragma unroll
                for (int r = 0; r < 4; ++r)
                    obuf[(mi * 16 + quad * 4 + r) * 66 + nd * 16 + l15] = o_acc[mi][nd][r];
    }
    __syncthreads();
    if (wid == 1) {
        #pragma unroll
        for (int mi = 0; mi < 4; ++mi)
            #pragma unroll
            for (int nd = 0; nd < 4; ++nd)
                #pragma unroll
                for (int r = 0; r < 4; ++r)
                    obuf[(mi * 16 + quad * 4 + r) * 66 + nd * 16 + l15] += o_acc[mi][nd][r];
    }
    __syncthreads();
    if (wid == 2) {
        #pragma unroll
        for (int mi = 0; mi < 4; ++mi)
            #pragma unroll
            for (int nd = 0; nd < 4; ++nd)
                #pragma unroll
                for (int r = 0; r < 4; ++r)
                    obuf[(mi * 16 + quad * 4 + r) * 66 + nd * 16 + l15] += o_acc[mi][nd][r];
    }
    __syncthreads();
    if (wid == 3) {
        #pragma unroll
        for (int mi = 0; mi < 4; ++mi) {
            #pragma unroll
            for (int r = 0; r < 4; ++r) {
                int row = mi * 16 + quad * 4 + r;
                float L = lbuf[0][row] + lbuf[1][row] + lbuf[2][row] + lbuf[3][row];
                float rinv = 1.0f / L;
                #pragma unroll
                for (int nd = 0; nd < 4; ++nd) {
                    float tot = obuf[row * 66 + nd * 16 + l15] + o_acc[mi][nd][r];
                    Om[((size_t)b * SEQ + q0 + row) * HID + h * DKK + nd * 16 + l15] =
                        f32_bf16(tot * rinv);
                }
            }
        }
    }
}

// ---------------------------------------------------------------------------
// Kernel 3: out = Om @ Wo^T + bo (fp32 output), LDS-free like proj.
// ---------------------------------------------------------------------------
__global__ __launch_bounds__(256, 2)
void outproj_kernel(const unsigned short* __restrict__ Om, const float* __restrict__ Wo,
                    const float* __restrict__ bo_, float* __restrict__ out)
{
    const int m0 = blockIdx.x * 128;
    const int n0 = blockIdx.y * 128;
    const int tid  = threadIdx.x;
    const int lane = tid & 63, wid = tid >> 6;
    const int wm = (wid >> 1) * 64, wn = (wid & 1) * 64;
    const int l15 = lane & 15, quad = lane >> 4;

    const unsigned short* Arow[4];
    const float* Brow[4];
    #pragma unroll
    for (int i = 0; i < 4; ++i) {
        Arow[i] = Om + (size_t)(m0 + wm + i * 16 + l15) * HID + quad * 8;
        Brow[i] = Wo + (size_t)(n0 + wn + i * 16 + l15) * HID + quad * 8;
    }

    f32x4 acc[4][4];
    #pragma unroll
    for (int i = 0; i < 4; ++i)
        #pragma unroll
        for (int j = 0; j < 4; ++j)
            acc[i][j] = f32x4{0.f, 0.f, 0.f, 0.f};

    for (int k0 = 0; k0 < HID; k0 += 32) {
        bf16x8 af[4], bfr[4];
        #pragma unroll
        for (int mi = 0; mi < 4; ++mi) af[mi] = *(const bf16x8*)(Arow[mi] + k0);
        #pragma unroll
        for (int ni = 0; ni < 4; ++ni) bfr[ni] = load_f32x8_bf16(Brow[ni] + k0);
        #pragma unroll
        for (int mi = 0; mi < 4; ++mi)
            #pragma unroll
            for (int ni = 0; ni < 4; ++ni)
                acc[mi][ni] = __builtin_amdgcn_mfma_f32_16x16x32_bf16(
                    af[mi], bfr[ni], acc[mi][ni], 0, 0, 0);
    }

    #pragma unroll
    for (int mi = 0; mi < 4; ++mi) {
        #pragma unroll
        for (int ni = 0; ni < 4; ++ni) {
            int n = n0 + wn + ni * 16 + l15;
            float bv = bo_[n];
            #pragma unroll
            for (int r = 0; r < 4; ++r) {
                int m = m0 + wm + mi * 16 + quad * 4 + r;
                out[(size_t)m * HID + n] = acc[mi][ni][r] + bv;
            }
        }
    }
}

// ---------------------------------------------------------------------------
extern "C" void kernel_launch(void* const* d_in, const int* in_sizes, int n_in,
                              void* d_out, int out_size, void* d_ws, size_t ws_size,
                              hipStream_t stream) {
    const float* q    = (const float*)d_in[0];
    const float* k    = (const float*)d_in[1];
    const float* v    = (const float*)d_in[2];
    const int*   mask = (const int*)  d_in[3];
    const float* Wq   = (const float*)d_in[4];
    const float* bq   = (const float*)d_in[5];
    const float* Wk   = (const float*)d_in[6];
    const float* bk   = (const float*)d_in[7];
    const float* Wv   = (const float*)d_in[8];
    const float* bv   = (const float*)d_in[9];
    const float* Wo   = (const float*)d_in[10];
    const float* bo   = (const float*)d_in[11];
    float* out = (float*)d_out;

    unsigned short* ws = (unsigned short*)d_ws;
    unsigned short* Qh = ws;
    unsigned short* Kh = ws + 8388608;
    unsigned short* Vt = ws + 16777216;
    unsigned short* Om = ws + 25165824;

    proj_kernel<<<dim3(32, 8, 3), 256, 0, stream>>>(q, k, v, Wq, bq, Wk, bk, Wv, bv,
                                                    Qh, Kh, Vt);
    attn_kernel<<<dim3(32, NHEAD, 2), 256, 0, stream>>>(Qh, Kh, Vt, mask, Om);
    outproj_kernel<<<dim3(32, 8, 1), 256, 0, stream>>>(Om, Wo, bo, out);
}

// Round 5
// 361.310 us; speedup vs baseline: 1.5059x; 1.5059x over previous
//
#include <hip/hip_runtime.h>

#define SEQ   2048
#define NHEAD 16
#define DKK   64
#define HID   1024

typedef __attribute__((ext_vector_type(8))) short bf16x8;
typedef __attribute__((ext_vector_type(4))) float f32x4;

__device__ __forceinline__ unsigned short f32_bf16(float f) {
    unsigned int u = __builtin_bit_cast(unsigned int, f);
    u += 0x7fffu + ((u >> 16) & 1u);
    return (unsigned short)(u >> 16);
}

__device__ __forceinline__ unsigned int pack_bf16x2(float a, float b) {
    return (unsigned int)f32_bf16(a) | ((unsigned int)f32_bf16(b) << 16);
}

// ---------------------------------------------------------------------------
// Kernel 0: bit-pack the int32 mask into u64 words (bit k%64 of word k/64).
// Memory-bound: reads 32 MB, writes 1 MB.
// ---------------------------------------------------------------------------
__global__ __launch_bounds__(256)
void mask_pack_kernel(const int* __restrict__ mask, unsigned long long* __restrict__ Mb)
{
    int idx = blockIdx.x * 256 + threadIdx.x;        // word index, B*S*S/64 total
    const int* src = mask + (size_t)idx * 64;
    unsigned long long w = 0;
    #pragma unroll
    for (int i = 0; i < 16; ++i) {
        int4 m4 = *(const int4*)(src + i * 4);
        w |= (unsigned long long)(m4.x != 0) << (i * 4 + 0);
        w |= (unsigned long long)(m4.y != 0) << (i * 4 + 1);
        w |= (unsigned long long)(m4.z != 0) << (i * 4 + 2);
        w |= (unsigned long long)(m4.w != 0) << (i * 4 + 3);
    }
    Mb[idx] = w;
}

// ---------------------------------------------------------------------------
// Kernel 1: QKV projections (LDS-staged, round-3 structure).  Y = X@W^T+bias,
// cast bf16, scattered to per-head layouts: Qh/Kh=[b,h,s,d]; Vt=[b,h,d,s].
// ---------------------------------------------------------------------------
__global__ __launch_bounds__(256, 2)
void proj_kernel(const float* __restrict__ qin, const float* __restrict__ kin,
                 const float* __restrict__ vin,
                 const float* __restrict__ Wq, const float* __restrict__ bq_,
                 const float* __restrict__ Wk, const float* __restrict__ bk_,
                 const float* __restrict__ Wv, const float* __restrict__ bv_,
                 unsigned short* __restrict__ Qh, unsigned short* __restrict__ Kh,
                 unsigned short* __restrict__ Vt)
{
    const int z = blockIdx.z;
    const float* X; const float* W; const float* bias;
    if (z == 0)      { X = qin; W = Wq; bias = bq_; }
    else if (z == 1) { X = kin; W = Wk; bias = bk_; }
    else             { X = vin; W = Wv; bias = bv_; }

    const int m0 = blockIdx.x * 128;
    const int n0 = blockIdx.y * 128;
    const int tid  = threadIdx.x;
    const int lane = tid & 63, wid = tid >> 6;
    const int wm = (wid >> 1) * 64, wn = (wid & 1) * 64;
    const int l15 = lane & 15, quad = lane >> 4;

    __shared__ __align__(16) unsigned short As[128 * 40];
    __shared__ __align__(16) unsigned short Bs[128 * 40];

    f32x4 acc[4][4];
    #pragma unroll
    for (int i = 0; i < 4; ++i)
        #pragma unroll
        for (int j = 0; j < 4; ++j)
            acc[i][j] = f32x4{0.f, 0.f, 0.f, 0.f};

    for (int k0 = 0; k0 < HID; k0 += 32) {
        __syncthreads();
        #pragma unroll
        for (int p = 0; p < 4; ++p) {
            int c = tid + p * 256;
            int row = c >> 3, c4 = c & 7;
            float4 a = *(const float4*)(X + (size_t)(m0 + row) * HID + k0 + c4 * 4);
            *(uint2*)&As[row * 40 + c4 * 4] =
                make_uint2(pack_bf16x2(a.x, a.y), pack_bf16x2(a.z, a.w));
            float4 b = *(const float4*)(W + (size_t)(n0 + row) * HID + k0 + c4 * 4);
            *(uint2*)&Bs[row * 40 + c4 * 4] =
                make_uint2(pack_bf16x2(b.x, b.y), pack_bf16x2(b.z, b.w));
        }
        __syncthreads();

        bf16x8 af[4], bfr[4];
        #pragma unroll
        for (int mi = 0; mi < 4; ++mi)
            af[mi] = *(const bf16x8*)&As[(wm + mi * 16 + l15) * 40 + quad * 8];
        #pragma unroll
        for (int ni = 0; ni < 4; ++ni)
            bfr[ni] = *(const bf16x8*)&Bs[(wn + ni * 16 + l15) * 40 + quad * 8];
        #pragma unroll
        for (int mi = 0; mi < 4; ++mi)
            #pragma unroll
            for (int ni = 0; ni < 4; ++ni)
                acc[mi][ni] = __builtin_amdgcn_mfma_f32_16x16x32_bf16(
                    af[mi], bfr[ni], acc[mi][ni], 0, 0, 0);
    }

    #pragma unroll
    for (int mi = 0; mi < 4; ++mi) {
        #pragma unroll
        for (int ni = 0; ni < 4; ++ni) {
            int n = n0 + wn + ni * 16 + l15;
            float bv = bias[n];
            int hh = n >> 6, d = n & 63;
            #pragma unroll
            for (int r = 0; r < 4; ++r) {
                int m = m0 + wm + mi * 16 + quad * 4 + r;
                int bb = m >> 11, s = m & 2047;
                unsigned short hv = f32_bf16(acc[mi][ni][r] + bv);
                if (z == 0)
                    Qh[((size_t)(bb * NHEAD + hh) * SEQ + s) * DKK + d] = hv;
                else if (z == 1)
                    Kh[((size_t)(bb * NHEAD + hh) * SEQ + s) * DKK + d] = hv;
                else
                    Vt[((size_t)(bb * NHEAD + hh) * DKK + d) * SEQ + s] = hv;
            }
        }
    }
}

// ---------------------------------------------------------------------------
// Kernel 2: split-K flash attention, no max tracking (logits bounded; masked
// logits are 1e-9 per reference => p = mask ? exp(s/8) : 1.0).  Block = 4
// waves over ONE 64-row q-tile; wave w handles k-tiles [8w, 8w+8).  K/V
// fragments load directly from global; zero block barriers in the k-loop.
// Mask comes from the bit-packed Mb: one broadcast u64 per (strip,row) --
// 16 loads per 64x64 tile instead of 64 scattered dwords per lane.
// Row sums via ones-MFMA; merge = plain sum of (O, l) partials.
// ---------------------------------------------------------------------------
__global__ __launch_bounds__(256, 2)
void attn_kernel(const unsigned short* __restrict__ Qh, const unsigned short* __restrict__ Kh,
                 const unsigned short* __restrict__ Vt,
                 const unsigned long long* __restrict__ Mb,
                 unsigned short* __restrict__ Om)
{
    const int qt = blockIdx.x;       // 0..31 (q-tile of 64)
    const int h  = blockIdx.y;
    const int b  = blockIdx.z;
    const int tid  = threadIdx.x;
    const int lane = tid & 63, wid = tid >> 6;
    const int l15 = lane & 15, quad = lane >> 4;
    const int q0 = qt * 64;

    const size_t hoff = (size_t)(b * NHEAD + h) * SEQ * DKK;
    const unsigned short* Qp = Qh + hoff;
    const unsigned short* Kp = Kh + hoff;
    const unsigned short* Vp = Vt + hoff;   // [d][s]

    __shared__ __align__(16) unsigned short Ps[4][64 * 72];  // per-wave P buffer
    __shared__ float lbuf[4][64];
    float* obuf = (float*)&Ps[0][0];        // 64x66 f32 merge buffer (aliased)

    // Q fragments (A-operand layout), same q-tile for all 4 waves
    bf16x8 qf[4][2];
    #pragma unroll
    for (int mi = 0; mi < 4; ++mi)
        #pragma unroll
        for (int kc = 0; kc < 2; ++kc)
            qf[mi][kc] = *(const bf16x8*)(Qp + (size_t)(q0 + mi * 16 + l15) * DKK
                                          + kc * 32 + quad * 8);

    // ones B-fragment for row-sum MFMA
    bf16x8 onesf;
    #pragma unroll
    for (int i = 0; i < 8; ++i) onesf[i] = (short)0x3F80;

    f32x4 o_acc[4][4];
    f32x4 l_acc[4];
    #pragma unroll
    for (int mi = 0; mi < 4; ++mi) {
        #pragma unroll
        for (int nd = 0; nd < 4; ++nd) o_acc[mi][nd] = f32x4{0.f, 0.f, 0.f, 0.f};
        l_acc[mi] = f32x4{0.f, 0.f, 0.f, 0.f};
    }

    const float C = 0.125f * 1.44269504f;   // 1/sqrt(dk) * log2(e)

    // per-lane base into the bitmask: rows q0.., this lane's quad row group
    const unsigned long long* Mrow = Mb + ((size_t)b * SEQ + q0 + quad * 4) * (SEQ / 64);

    const int ktBeg = wid * 8, ktEnd = ktBeg + 8;
    for (int kt = ktBeg; kt < ktEnd; ++kt) {
        const int kbase = kt * 64;
        // K and V fragments (B-operand) straight from global
        bf16x8 kb[2][4], vb[2][4];
        #pragma unroll
        for (int kc = 0; kc < 2; ++kc)
            #pragma unroll
            for (int ni = 0; ni < 4; ++ni) {
                kb[kc][ni] = *(const bf16x8*)(Kp + (size_t)(kbase + ni * 16 + l15) * DKK
                                              + kc * 32 + quad * 8);
                vb[kc][ni] = *(const bf16x8*)(Vp + (size_t)(ni * 16 + l15) * SEQ
                                              + kbase + kc * 32 + quad * 8);
            }

        #pragma unroll
        for (int mi = 0; mi < 4; ++mi) {
            // mask bits for this 16-row strip: one broadcast u64 per row,
            // shifted so this lane's 4 columns sit at bits 0/16/32/48
            unsigned long long mw[4];
            #pragma unroll
            for (int r = 0; r < 4; ++r)
                mw[r] = Mrow[(size_t)(mi * 16 + r) * (SEQ / 64) + kt] >> l15;

            f32x4 s[4];
            #pragma unroll
            for (int ni = 0; ni < 4; ++ni) s[ni] = f32x4{0.f, 0.f, 0.f, 0.f};
            #pragma unroll
            for (int kc = 0; kc < 2; ++kc)
                #pragma unroll
                for (int ni = 0; ni < 4; ++ni)
                    s[ni] = __builtin_amdgcn_mfma_f32_16x16x32_bf16(
                        qf[mi][kc], kb[kc][ni], s[ni], 0, 0, 0);

            // p = bit ? exp2(s*C) : 1.0   (fixed max = 0; masked logit 1e-9 -> p=1)
            #pragma unroll
            for (int r = 0; r < 4; ++r) {
                unsigned short* prow = &Ps[wid][(mi * 16 + quad * 4 + r) * 72];
                #pragma unroll
                for (int ni = 0; ni < 4; ++ni) {
                    float e = exp2f(s[ni][r] * C);
                    float p = (mw[r] >> (ni * 16)) & 1 ? e : 1.0f;
                    prow[ni * 16 + l15] = f32_bf16(p);
                }
            }

            // O += P V ; l += P @ 1   (compiler inserts the lgkm waits)
            #pragma unroll
            for (int kc = 0; kc < 2; ++kc) {
                bf16x8 pa = *(const bf16x8*)&Ps[wid][(mi * 16 + l15) * 72 + kc * 32 + quad * 8];
                l_acc[mi] = __builtin_amdgcn_mfma_f32_16x16x32_bf16(
                    pa, onesf, l_acc[mi], 0, 0, 0);
                #pragma unroll
                for (int nd = 0; nd < 4; ++nd)
                    o_acc[mi][nd] = __builtin_amdgcn_mfma_f32_16x16x32_bf16(
                        pa, vb[kc][nd], o_acc[mi][nd], 0, 0, 0);
            }
        }
    }

    // ---- merge 4 per-wave partial (O, l) by plain summation ----
    if (l15 == 0) {
        #pragma unroll
        for (int mi = 0; mi < 4; ++mi)
            #pragma unroll
            for (int r = 0; r < 4; ++r)
                lbuf[wid][mi * 16 + quad * 4 + r] = l_acc[mi][r];
    }
    __syncthreads();   // also fences last Ps reads before obuf aliasing

    if (wid == 0) {
        #pragma unroll
        for (int mi = 0; mi < 4; ++mi)
            #pragma unroll
            for (int nd = 0; nd < 4; ++nd)
                #pragma unroll
                for (int r = 0; r < 4; ++r)
                    obuf[(mi * 16 + quad * 4 + r) * 66 + nd * 16 + l15] = o_acc[mi][nd][r];
    }
    __syncthreads();
    if (wid == 1) {
        #pragma unroll
        for (int mi = 0; mi < 4; ++mi)
            #pragma unroll
            for (int nd = 0; nd < 4; ++nd)
                #pragma unroll
                for (int r = 0; r < 4; ++r)
                    obuf[(mi * 16 + quad * 4 + r) * 66 + nd * 16 + l15] += o_acc[mi][nd][r];
    }
    __syncthreads();
    if (wid == 2) {
        #pragma unroll
        for (int mi = 0; mi < 4; ++mi)
            #pragma unroll
            for (int nd = 0; nd < 4; ++nd)
                #pragma unroll
                for (int r = 0; r < 4; ++r)
                    obuf[(mi * 16 + quad * 4 + r) * 66 + nd * 16 + l15] += o_acc[mi][nd][r];
    }
    __syncthreads();
    if (wid == 3) {
        #pragma unroll
        for (int mi = 0; mi < 4; ++mi) {
            #pragma unroll
            for (int r = 0; r < 4; ++r) {
                int row = mi * 16 + quad * 4 + r;
                float L = lbuf[0][row] + lbuf[1][row] + lbuf[2][row] + lbuf[3][row];
                float rinv = 1.0f / L;
                #pragma unroll
                for (int nd = 0; nd < 4; ++nd) {
                    float tot = obuf[row * 66 + nd * 16 + l15] + o_acc[mi][nd][r];
                    Om[((size_t)b * SEQ + q0 + row) * HID + h * DKK + nd * 16 + l15] =
                        f32_bf16(tot * rinv);
                }
            }
        }
    }
}

// ---------------------------------------------------------------------------
// Kernel 3: out = Om @ Wo^T + bo (fp32 output), LDS-staged (round-3).
// ---------------------------------------------------------------------------
__global__ __launch_bounds__(256, 2)
void outproj_kernel(const unsigned short* __restrict__ Om, const float* __restrict__ Wo,
                    const float* __restrict__ bo_, float* __restrict__ out)
{
    const int m0 = blockIdx.x * 128;
    const int n0 = blockIdx.y * 128;
    const int tid  = threadIdx.x;
    const int lane = tid & 63, wid = tid >> 6;
    const int wm = (wid >> 1) * 64, wn = (wid & 1) * 64;
    const int l15 = lane & 15, quad = lane >> 4;

    __shared__ __align__(16) unsigned short As[128 * 40];
    __shared__ __align__(16) unsigned short Bs[128 * 40];

    f32x4 acc[4][4];
    #pragma unroll
    for (int i = 0; i < 4; ++i)
        #pragma unroll
        for (int j = 0; j < 4; ++j)
            acc[i][j] = f32x4{0.f, 0.f, 0.f, 0.f};

    for (int k0 = 0; k0 < HID; k0 += 32) {
        __syncthreads();
        #pragma unroll
        for (int p = 0; p < 2; ++p) {
            int c = tid + p * 256;
            int row = c >> 2, c8 = c & 3;
            *(uint4*)&As[row * 40 + c8 * 8] =
                *(const uint4*)(Om + (size_t)(m0 + row) * HID + k0 + c8 * 8);
        }
        #pragma unroll
        for (int p = 0; p < 4; ++p) {
            int c = tid + p * 256;
            int row = c >> 3, c4 = c & 7;
            float4 b = *(const float4*)(Wo + (size_t)(n0 + row) * HID + k0 + c4 * 4);
            *(uint2*)&Bs[row * 40 + c4 * 4] =
                make_uint2(pack_bf16x2(b.x, b.y), pack_bf16x2(b.z, b.w));
        }
        __syncthreads();

        bf16x8 af[4], bfr[4];
        #pragma unroll
        for (int mi = 0; mi < 4; ++mi)
            af[mi] = *(const bf16x8*)&As[(wm + mi * 16 + l15) * 40 + quad * 8];
        #pragma unroll
        for (int ni = 0; ni < 4; ++ni)
            bfr[ni] = *(const bf16x8*)&Bs[(wn + ni * 16 + l15) * 40 + quad * 8];
        #pragma unroll
        for (int mi = 0; mi < 4; ++mi)
            #pragma unroll
            for (int ni = 0; ni < 4; ++ni)
                acc[mi][ni] = __builtin_amdgcn_mfma_f32_16x16x32_bf16(
                    af[mi], bfr[ni], acc[mi][ni], 0, 0, 0);
    }

    #pragma unroll
    for (int mi = 0; mi < 4; ++mi) {
        #pragma unroll
        for (int ni = 0; ni < 4; ++ni) {
            int n = n0 + wn + ni * 16 + l15;
            float bv = bo_[n];
            #pragma unroll
            for (int r = 0; r < 4; ++r) {
                int m = m0 + wm + mi * 16 + quad * 4 + r;
                out[(size_t)m * HID + n] = acc[mi][ni][r] + bv;
            }
        }
    }
}

// ---------------------------------------------------------------------------
extern "C" void kernel_launch(void* const* d_in, const int* in_sizes, int n_in,
                              void* d_out, int out_size, void* d_ws, size_t ws_size,
                              hipStream_t stream) {
    const float* q    = (const float*)d_in[0];
    const float* k    = (const float*)d_in[1];
    const float* v    = (const float*)d_in[2];
    const int*   mask = (const int*)  d_in[3];
    const float* Wq   = (const float*)d_in[4];
    const float* bq   = (const float*)d_in[5];
    const float* Wk   = (const float*)d_in[6];
    const float* bk   = (const float*)d_in[7];
    const float* Wv   = (const float*)d_in[8];
    const float* bv   = (const float*)d_in[9];
    const float* Wo   = (const float*)d_in[10];
    const float* bo   = (const float*)d_in[11];
    float* out = (float*)d_out;

    // workspace (bf16 elems): Qh | Kh | Vt | Om (each 8388608) then Mb (u64)
    unsigned short* ws = (unsigned short*)d_ws;
    unsigned short* Qh = ws;
    unsigned short* Kh = ws + 8388608;
    unsigned short* Vt = ws + 16777216;
    unsigned short* Om = ws + 25165824;
    unsigned long long* Mb = (unsigned long long*)(ws + 33554432);  // 1 MB

    mask_pack_kernel<<<dim3(2 * SEQ * (SEQ / 64) / 256), 256, 0, stream>>>(mask, Mb);
    proj_kernel<<<dim3(32, 8, 3), 256, 0, stream>>>(q, k, v, Wq, bq, Wk, bk, Wv, bv,
                                                    Qh, Kh, Vt);
    attn_kernel<<<dim3(32, NHEAD, 2), 256, 0, stream>>>(Qh, Kh, Vt, Mb, Om);
    outproj_kernel<<<dim3(32, 8, 1), 256, 0, stream>>>(Om, Wo, bo, out);
}

// Round 6
// 339.980 us; speedup vs baseline: 1.6004x; 1.0627x over previous
//
#include <hip/hip_runtime.h>

#define SEQ   2048
#define NHEAD 16
#define DKK   64
#define HID   1024

typedef __attribute__((ext_vector_type(8))) short bf16x8;
typedef __attribute__((ext_vector_type(4))) float f32x4;

__device__ __forceinline__ unsigned short f32_bf16(float f) {
    unsigned int u = __builtin_bit_cast(unsigned int, f);
    u += 0x7fffu + ((u >> 16) & 1u);
    return (unsigned short)(u >> 16);
}

__device__ __forceinline__ unsigned int pack_bf16x2(float a, float b) {
    return (unsigned int)f32_bf16(a) | ((unsigned int)f32_bf16(b) << 16);
}

// async global->LDS 16B copy (DMA, no VGPR round-trip)
__device__ __forceinline__ void glds16(const void* g, void* l) {
    __builtin_amdgcn_global_load_lds(
        (const __attribute__((address_space(1))) unsigned int*)g,
        (__attribute__((address_space(3))) unsigned int*)l, 16, 0, 0);
}

// ---------------------------------------------------------------------------
// Kernel A: fp32 -> bf16 bulk convert (memory-bound prepass).
// ---------------------------------------------------------------------------
__global__ __launch_bounds__(256)
void cvt_kernel(const float* __restrict__ src, unsigned short* __restrict__ dst, int n4)
{
    int i = blockIdx.x * 256 + threadIdx.x;
    if (i >= n4) return;
    float4 a = ((const float4*)src)[i];
    ((uint2*)dst)[i] = make_uint2(pack_bf16x2(a.x, a.y), pack_bf16x2(a.z, a.w));
}

// ---------------------------------------------------------------------------
// Kernel B: bit-pack the int32 mask into u64 words (bit k%64 of word k/64).
// ---------------------------------------------------------------------------
__global__ __launch_bounds__(256)
void mask_pack_kernel(const int* __restrict__ mask, unsigned long long* __restrict__ Mb)
{
    int idx = blockIdx.x * 256 + threadIdx.x;
    const int* src = mask + (size_t)idx * 64;
    unsigned long long w = 0;
    #pragma unroll
    for (int i = 0; i < 16; ++i) {
        int4 m4 = *(const int4*)(src + i * 4);
        w |= (unsigned long long)(m4.x != 0) << (i * 4 + 0);
        w |= (unsigned long long)(m4.y != 0) << (i * 4 + 1);
        w |= (unsigned long long)(m4.z != 0) << (i * 4 + 2);
        w |= (unsigned long long)(m4.w != 0) << (i * 4 + 3);
    }
    Mb[idx] = w;
}

// ---------------------------------------------------------------------------
// Kernel 1: QKV projections, m97-structure: global_load_lds width-16 staging,
// BK=32, 2-barrier K-loop, XOR col-group swizzle (8-way -> 4-way ds_read
// conflicts).  All operands pre-converted bf16.  Epilogue scatters to
// Qh/Kh=[b,h,s,d], Vt=[b,h,d,s].
// ---------------------------------------------------------------------------
__global__ __launch_bounds__(256, 2)
void proj_kernel(const unsigned short* __restrict__ xq, const unsigned short* __restrict__ xk,
                 const unsigned short* __restrict__ xv,
                 const unsigned short* __restrict__ Wqb, const unsigned short* __restrict__ Wkb,
                 const unsigned short* __restrict__ Wvb,
                 const float* __restrict__ bq_, const float* __restrict__ bk_,
                 const float* __restrict__ bv_,
                 unsigned short* __restrict__ Qh, unsigned short* __restrict__ Kh,
                 unsigned short* __restrict__ Vt)
{
    const int z = blockIdx.z;
    const unsigned short* X; const unsigned short* W; const float* bias;
    if (z == 0)      { X = xq; W = Wqb; bias = bq_; }
    else if (z == 1) { X = xk; W = Wkb; bias = bk_; }
    else             { X = xv; W = Wvb; bias = bv_; }

    const int m0 = blockIdx.x * 128;
    const int n0 = blockIdx.y * 128;
    const int tid  = threadIdx.x;
    const int lane = tid & 63, wid = tid >> 6;
    const int wm = (wid >> 1) * 64, wn = (wid & 1) * 64;
    const int l15 = lane & 15, quad = lane >> 4;

    __shared__ __align__(16) unsigned short As[128 * 32];   // 8 KB, unpadded
    __shared__ __align__(16) unsigned short Bs[128 * 32];

    // staging descriptors: chunk c = tid (+256); row=c>>2, cg=c&3;
    // LDS slot (row,cg) holds global col-group cg^(row&3)  (XOR swizzle)
    const int r0 = tid >> 2, cg = tid & 3;
    const unsigned short* gA = X + (size_t)(m0 + r0) * HID + ((cg ^ (r0 & 3)) * 8);
    const unsigned short* gB = W + (size_t)(n0 + r0) * HID + ((cg ^ (r0 & 3)) * 8);
    unsigned short* lA0 = &As[tid * 8];
    unsigned short* lA1 = &As[(tid + 256) * 8];
    unsigned short* lB0 = &Bs[tid * 8];
    unsigned short* lB1 = &Bs[(tid + 256) * 8];

    // fragment read col-group (swizzle-consistent), constant per lane
    const int cgsel = (quad ^ (l15 & 3)) * 8;

    f32x4 acc[4][4];
    #pragma unroll
    for (int i = 0; i < 4; ++i)
        #pragma unroll
        for (int j = 0; j < 4; ++j)
            acc[i][j] = f32x4{0.f, 0.f, 0.f, 0.f};

    for (int k0 = 0; k0 < HID; k0 += 32) {
        glds16(gA + k0, lA0);
        glds16(gA + (size_t)64 * HID + k0, lA1);
        glds16(gB + k0, lB0);
        glds16(gB + (size_t)64 * HID + k0, lB1);
        __syncthreads();                       // drains vmcnt: staged data visible

        bf16x8 af[4], bfr[4];
        #pragma unroll
        for (int mi = 0; mi < 4; ++mi)
            af[mi] = *(const bf16x8*)&As[(wm + mi * 16 + l15) * 32 + cgsel];
        #pragma unroll
        for (int ni = 0; ni < 4; ++ni)
            bfr[ni] = *(const bf16x8*)&Bs[(wn + ni * 16 + l15) * 32 + cgsel];
        #pragma unroll
        for (int mi = 0; mi < 4; ++mi)
            #pragma unroll
            for (int ni = 0; ni < 4; ++ni)
                acc[mi][ni] = __builtin_amdgcn_mfma_f32_16x16x32_bf16(
                    af[mi], bfr[ni], acc[mi][ni], 0, 0, 0);
        __syncthreads();                       // reads done before next overwrite
    }

    #pragma unroll
    for (int mi = 0; mi < 4; ++mi) {
        #pragma unroll
        for (int ni = 0; ni < 4; ++ni) {
            int n = n0 + wn + ni * 16 + l15;
            float bv = bias[n];
            int hh = n >> 6, d = n & 63;
            #pragma unroll
            for (int r = 0; r < 4; ++r) {
                int m = m0 + wm + mi * 16 + quad * 4 + r;
                int bb = m >> 11, s = m & 2047;
                unsigned short hv = f32_bf16(acc[mi][ni][r] + bv);
                if (z == 0)
                    Qh[((size_t)(bb * NHEAD + hh) * SEQ + s) * DKK + d] = hv;
                else if (z == 1)
                    Kh[((size_t)(bb * NHEAD + hh) * SEQ + s) * DKK + d] = hv;
                else
                    Vt[((size_t)(bb * NHEAD + hh) * DKK + d) * SEQ + s] = hv;
            }
        }
    }
}

// ---------------------------------------------------------------------------
// Kernel 2: split-K flash attention (unchanged from round 5).
// ---------------------------------------------------------------------------
__global__ __launch_bounds__(256, 2)
void attn_kernel(const unsigned short* __restrict__ Qh, const unsigned short* __restrict__ Kh,
                 const unsigned short* __restrict__ Vt,
                 const unsigned long long* __restrict__ Mb,
                 unsigned short* __restrict__ Om)
{
    const int qt = blockIdx.x;       // 0..31 (q-tile of 64)
    const int h  = blockIdx.y;
    const int b  = blockIdx.z;
    const int tid  = threadIdx.x;
    const int lane = tid & 63, wid = tid >> 6;
    const int l15 = lane & 15, quad = lane >> 4;
    const int q0 = qt * 64;

    const size_t hoff = (size_t)(b * NHEAD + h) * SEQ * DKK;
    const unsigned short* Qp = Qh + hoff;
    const unsigned short* Kp = Kh + hoff;
    const unsigned short* Vp = Vt + hoff;   // [d][s]

    __shared__ __align__(16) unsigned short Ps[4][64 * 72];
    __shared__ float lbuf[4][64];
    float* obuf = (float*)&Ps[0][0];

    bf16x8 qf[4][2];
    #pragma unroll
    for (int mi = 0; mi < 4; ++mi)
        #pragma unroll
        for (int kc = 0; kc < 2; ++kc)
            qf[mi][kc] = *(const bf16x8*)(Qp + (size_t)(q0 + mi * 16 + l15) * DKK
                                          + kc * 32 + quad * 8);

    bf16x8 onesf;
    #pragma unroll
    for (int i = 0; i < 8; ++i) onesf[i] = (short)0x3F80;

    f32x4 o_acc[4][4];
    f32x4 l_acc[4];
    #pragma unroll
    for (int mi = 0; mi < 4; ++mi) {
        #pragma unroll
        for (int nd = 0; nd < 4; ++nd) o_acc[mi][nd] = f32x4{0.f, 0.f, 0.f, 0.f};
        l_acc[mi] = f32x4{0.f, 0.f, 0.f, 0.f};
    }

    const float C = 0.125f * 1.44269504f;

    const unsigned long long* Mrow = Mb + ((size_t)b * SEQ + q0 + quad * 4) * (SEQ / 64);

    const int ktBeg = wid * 8, ktEnd = ktBeg + 8;
    for (int kt = ktBeg; kt < ktEnd; ++kt) {
        const int kbase = kt * 64;
        bf16x8 kb[2][4], vb[2][4];
        #pragma unroll
        for (int kc = 0; kc < 2; ++kc)
            #pragma unroll
            for (int ni = 0; ni < 4; ++ni) {
                kb[kc][ni] = *(const bf16x8*)(Kp + (size_t)(kbase + ni * 16 + l15) * DKK
                                              + kc * 32 + quad * 8);
                vb[kc][ni] = *(const bf16x8*)(Vp + (size_t)(ni * 16 + l15) * SEQ
                                              + kbase + kc * 32 + quad * 8);
            }

        #pragma unroll
        for (int mi = 0; mi < 4; ++mi) {
            unsigned long long mw[4];
            #pragma unroll
            for (int r = 0; r < 4; ++r)
                mw[r] = Mrow[(size_t)(mi * 16 + r) * (SEQ / 64) + kt] >> l15;

            f32x4 s[4];
            #pragma unroll
            for (int ni = 0; ni < 4; ++ni) s[ni] = f32x4{0.f, 0.f, 0.f, 0.f};
            #pragma unroll
            for (int kc = 0; kc < 2; ++kc)
                #pragma unroll
                for (int ni = 0; ni < 4; ++ni)
                    s[ni] = __builtin_amdgcn_mfma_f32_16x16x32_bf16(
                        qf[mi][kc], kb[kc][ni], s[ni], 0, 0, 0);

            #pragma unroll
            for (int r = 0; r < 4; ++r) {
                unsigned short* prow = &Ps[wid][(mi * 16 + quad * 4 + r) * 72];
                #pragma unroll
                for (int ni = 0; ni < 4; ++ni) {
                    float e = exp2f(s[ni][r] * C);
                    float p = (mw[r] >> (ni * 16)) & 1 ? e : 1.0f;
                    prow[ni * 16 + l15] = f32_bf16(p);
                }
            }

            #pragma unroll
            for (int kc = 0; kc < 2; ++kc) {
                bf16x8 pa = *(const bf16x8*)&Ps[wid][(mi * 16 + l15) * 72 + kc * 32 + quad * 8];
                l_acc[mi] = __builtin_amdgcn_mfma_f32_16x16x32_bf16(
                    pa, onesf, l_acc[mi], 0, 0, 0);
                #pragma unroll
                for (int nd = 0; nd < 4; ++nd)
                    o_acc[mi][nd] = __builtin_amdgcn_mfma_f32_16x16x32_bf16(
                        pa, vb[kc][nd], o_acc[mi][nd], 0, 0, 0);
            }
        }
    }

    if (l15 == 0) {
        #pragma unroll
        for (int mi = 0; mi < 4; ++mi)
            #pragma unroll
            for (int r = 0; r < 4; ++r)
                lbuf[wid][mi * 16 + quad * 4 + r] = l_acc[mi][r];
    }
    __syncthreads();

    if (wid == 0) {
        #pragma unroll
        for (int mi = 0; mi < 4; ++mi)
            #pragma unroll
            for (int nd = 0; nd < 4; ++nd)
                #pragma unroll
                for (int r = 0; r < 4; ++r)
                    obuf[(mi * 16 + quad * 4 + r) * 66 + nd * 16 + l15] = o_acc[mi][nd][r];
    }
    __syncthreads();
    if (wid == 1) {
        #pragma unroll
        for (int mi = 0; mi < 4; ++mi)
            #pragma unroll
            for (int nd = 0; nd < 4; ++nd)
                #pragma unroll
                for (int r = 0; r < 4; ++r)
                    obuf[(mi * 16 + quad * 4 + r) * 66 + nd * 16 + l15] += o_acc[mi][nd][r];
    }
    __syncthreads();
    if (wid == 2) {
        #pragma unroll
        for (int mi = 0; mi < 4; ++mi)
            #pragma unroll
            for (int nd = 0; nd < 4; ++nd)
                #pragma unroll
                for (int r = 0; r < 4; ++r)
                    obuf[(mi * 16 + quad * 4 + r) * 66 + nd * 16 + l15] += o_acc[mi][nd][r];
    }
    __syncthreads();
    if (wid == 3) {
        #pragma unroll
        for (int mi = 0; mi < 4; ++mi) {
            #pragma unroll
            for (int r = 0; r < 4; ++r) {
                int row = mi * 16 + quad * 4 + r;
                float L = lbuf[0][row] + lbuf[1][row] + lbuf[2][row] + lbuf[3][row];
                float rinv = 1.0f / L;
                #pragma unroll
                for (int nd = 0; nd < 4; ++nd) {
                    float tot = obuf[row * 66 + nd * 16 + l15] + o_acc[mi][nd][r];
                    Om[((size_t)b * SEQ + q0 + row) * HID + h * DKK + nd * 16 + l15] =
                        f32_bf16(tot * rinv);
                }
            }
        }
    }
}

// ---------------------------------------------------------------------------
// Kernel 3: out = Om @ Wo^T + bo (fp32 out), m97-structure like proj.
// ---------------------------------------------------------------------------
__global__ __launch_bounds__(256, 2)
void outproj_kernel(const unsigned short* __restrict__ Om, const unsigned short* __restrict__ Wob,
                    const float* __restrict__ bo_, float* __restrict__ out)
{
    const int m0 = blockIdx.x * 128;
    const int n0 = blockIdx.y * 128;
    const int tid  = threadIdx.x;
    const int lane = tid & 63, wid = tid >> 6;
    const int wm = (wid >> 1) * 64, wn = (wid & 1) * 64;
    const int l15 = lane & 15, quad = lane >> 4;

    __shared__ __align__(16) unsigned short As[128 * 32];
    __shared__ __align__(16) unsigned short Bs[128 * 32];

    const int r0 = tid >> 2, cg = tid & 3;
    const unsigned short* gA = Om + (size_t)(m0 + r0) * HID + ((cg ^ (r0 & 3)) * 8);
    const unsigned short* gB = Wob + (size_t)(n0 + r0) * HID + ((cg ^ (r0 & 3)) * 8);
    unsigned short* lA0 = &As[tid * 8];
    unsigned short* lA1 = &As[(tid + 256) * 8];
    unsigned short* lB0 = &Bs[tid * 8];
    unsigned short* lB1 = &Bs[(tid + 256) * 8];
    const int cgsel = (quad ^ (l15 & 3)) * 8;

    f32x4 acc[4][4];
    #pragma unroll
    for (int i = 0; i < 4; ++i)
        #pragma unroll
        for (int j = 0; j < 4; ++j)
            acc[i][j] = f32x4{0.f, 0.f, 0.f, 0.f};

    for (int k0 = 0; k0 < HID; k0 += 32) {
        glds16(gA + k0, lA0);
        glds16(gA + (size_t)64 * HID + k0, lA1);
        glds16(gB + k0, lB0);
        glds16(gB + (size_t)64 * HID + k0, lB1);
        __syncthreads();

        bf16x8 af[4], bfr[4];
        #pragma unroll
        for (int mi = 0; mi < 4; ++mi)
            af[mi] = *(const bf16x8*)&As[(wm + mi * 16 + l15) * 32 + cgsel];
        #pragma unroll
        for (int ni = 0; ni < 4; ++ni)
            bfr[ni] = *(const bf16x8*)&Bs[(wn + ni * 16 + l15) * 32 + cgsel];
        #pragma unroll
        for (int mi = 0; mi < 4; ++mi)
            #pragma unroll
            for (int ni = 0; ni < 4; ++ni)
                acc[mi][ni] = __builtin_amdgcn_mfma_f32_16x16x32_bf16(
                    af[mi], bfr[ni], acc[mi][ni], 0, 0, 0);
        __syncthreads();
    }

    #pragma unroll
    for (int mi = 0; mi < 4; ++mi) {
        #pragma unroll
        for (int ni = 0; ni < 4; ++ni) {
            int n = n0 + wn + ni * 16 + l15;
            float bv = bo_[n];
            #pragma unroll
            for (int r = 0; r < 4; ++r) {
                int m = m0 + wm + mi * 16 + quad * 4 + r;
                out[(size_t)m * HID + n] = acc[mi][ni][r] + bv;
            }
        }
    }
}

// ---------------------------------------------------------------------------
extern "C" void kernel_launch(void* const* d_in, const int* in_sizes, int n_in,
                              void* d_out, int out_size, void* d_ws, size_t ws_size,
                              hipStream_t stream) {
    const float* q    = (const float*)d_in[0];
    const float* k    = (const float*)d_in[1];
    const float* v    = (const float*)d_in[2];
    const int*   mask = (const int*)  d_in[3];
    const float* Wq   = (const float*)d_in[4];
    const float* bq   = (const float*)d_in[5];
    const float* Wk   = (const float*)d_in[6];
    const float* bk   = (const float*)d_in[7];
    const float* Wv   = (const float*)d_in[8];
    const float* bv   = (const float*)d_in[9];
    const float* Wo   = (const float*)d_in[10];
    const float* bo   = (const float*)d_in[11];
    float* out = (float*)d_out;

    // workspace layout (bf16 element offsets):
    unsigned short* ws  = (unsigned short*)d_ws;
    unsigned short* qb  = ws;                  // 4194304 elems (B*S*H)
    unsigned short* kbx = ws + 4194304;
    unsigned short* vbx = ws + 8388608;
    unsigned short* Wqb = ws + 12582912;       // 1048576 elems each
    unsigned short* Wkb = ws + 13631488;
    unsigned short* Wvb = ws + 14680064;
    unsigned short* Wob = ws + 15728640;
    unsigned short* Qh  = ws + 16777216;
    unsigned short* Kh  = ws + 20971520;
    unsigned short* Vt  = ws + 25165824;
    unsigned short* Om  = ws;                  // alias qb (dead after proj)
    unsigned long long* Mb = (unsigned long long*)(ws + 29360128);  // 1 MB

    const int n4x = 4194304 / 4, n4w = 1048576 / 4;
    mask_pack_kernel<<<dim3(2 * SEQ * (SEQ / 64) / 256), 256, 0, stream>>>(mask, Mb);
    cvt_kernel<<<dim3(n4x / 256), 256, 0, stream>>>(q, qb, n4x);
    cvt_kernel<<<dim3(n4x / 256), 256, 0, stream>>>(k, kbx, n4x);
    cvt_kernel<<<dim3(n4x / 256), 256, 0, stream>>>(v, vbx, n4x);
    cvt_kernel<<<dim3(n4w / 256), 256, 0, stream>>>(Wq, Wqb, n4w);
    cvt_kernel<<<dim3(n4w / 256), 256, 0, stream>>>(Wk, Wkb, n4w);
    cvt_kernel<<<dim3(n4w / 256), 256, 0, stream>>>(Wv, Wvb, n4w);
    cvt_kernel<<<dim3(n4w / 256), 256, 0, stream>>>(Wo, Wob, n4w);

    proj_kernel<<<dim3(32, 8, 3), 256, 0, stream>>>(qb, kbx, vbx, Wqb, Wkb, Wvb,
                                                    bq, bk, bv, Qh, Kh, Vt);
    attn_kernel<<<dim3(32, NHEAD, 2), 256, 0, stream>>>(Qh, Kh, Vt, Mb, Om);
    outproj_kernel<<<dim3(32, 8, 1), 256, 0, stream>>>(Om, Wob, bo, out);
}